// Round 10
// baseline (108.430 us; speedup 1.0000x reference)
//
#include <hip/hip_runtime.h>
#include <math.h>

#define N_ROWS 32768
#define DIM 64
#define KCOMP 64
#define KSPLIT 16
#define KLOCAL 4           // KCOMP / KSPLIT
#define THREADS 512        // 8 waves (R24: B-tile shared by 8 waves)
#define NWAVES 8
#define PREP_THREADS 256
#define RT 4               // row-tiles of 16 per wave
#define ROWS_PER_WAVE 64
#define ROWS_PER_BLOCK 512 // 8 waves * 64 rows
#define ROWGROUPS (N_ROWS / ROWS_PER_BLOCK)   // 64

// P is UPPER-TRIANGULAR (P[d][e]=0 for d>e): of the 8 (et,c) blocks,
// (et=0,c=1) and (et=1,c=1) are all-zero. Pt packs the 6 nonzero slots:
//   slot: 0=(et0,c0) 1=(et1,c0) 2=(et2,c0) 3=(et2,c1) 4=(et3,c0) 5=(et3,c1)
// Per k: 6 slots x 2048 B = 12288 B:
//   slot block: [hi: 64 chunks x 16 B, chunk=lane] [lo: same, +1024]
//   chunk(lane) holds f16 P[d = c*32 + q*8 + j][e = et*16 + m], j=0..7
// Skipping the zero blocks is BIT-IDENTICAL: mfma(0, B, acc) adds +/-0.
#define PT_K_BYTES 12288

#define LOG2PI_D 1.8378770664093454836

typedef _Float16 f16x8 __attribute__((ext_vector_type(8)));
typedef float f32x4 __attribute__((ext_vector_type(4)));

#define AS1 __attribute__((address_space(1)))
#define AS3 __attribute__((address_space(3)))

// async 16B/lane global->LDS DMA: lds dest wave-uniform; lane i -> base+i*16
__device__ __forceinline__ void async_copy16(const char* g, char* l) {
  __builtin_amdgcn_global_load_lds((const AS1 unsigned int*)g,
                                   (AS3 unsigned int*)l, 16, 0, 0);
}

// ---------------- digamma (double, recurrence + asymptotic) ----------------
__device__ __forceinline__ double digamma_d(double x) {
  double r = 0.0;
  while (x < 6.0) { r -= 1.0 / x; x += 1.0; }
  double inv = 1.0 / x;
  double inv2 = inv * inv;
  double s = log(x) - 0.5 * inv
      - inv2 * (1.0/12.0 - inv2 * (1.0/120.0 - inv2 * (1.0/252.0
      - inv2 * (1.0/240.0 - inv2 * (1.0/132.0)))));
  return r + s;
}

// ------- prep1: one block per k. LDS-staged transpose repack of P into Pt
//         (6 nonzero 16x16x32-slots, R22 map). Wave 0: muP, log-det,
//         digamma sums, stick-breaking. Also zeroes packed/cnt. -----------
__global__ void prep1_kernel(const float* __restrict__ means,
                             const float* __restrict__ P,
                             const float* __restrict__ wc,
                             const float* __restrict__ dof,
                             const float* __restrict__ mp,
                             char*   __restrict__ Pt,
                             float*  __restrict__ muP,
                             double* __restrict__ t_arr,
                             double* __restrict__ g_arr,
                             double* __restrict__ pc_arr,
                             uint4*  __restrict__ packed4,  // 16384 x 16 B
                             uint4*  __restrict__ cnt4)     // 64 x 16 B
{
  __shared__ float lds[DIM][DIM + 1];
  const int k = blockIdx.x;
  const int t = threadIdx.x;
  const float* Pk = P + k * DIM * DIM;

  // fused memset: zero packed (64 blk x 256 thr x 16 B = 256 KB) + cnt
  const uint4 z4 = {0u, 0u, 0u, 0u};
  packed4[k * PREP_THREADS + t] = z4;
  if (k == 0 && t < 64) cnt4[t] = z4;

  for (int i = t; i < DIM * DIM; i += PREP_THREADS)
    lds[i >> 6][i & 63] = Pk[i];
  __syncthreads();

  char* dst = Pt + (size_t)k * PT_K_BYTES;
#pragma unroll
  for (int cc = 0; cc < 3; ++cc) {                // 768 cids = 6 slots x 2 KB
    int cid  = cc * PREP_THREADS + t;
    int slot = cid >> 7;               // 0..5
    int sel  = (cid >> 6) & 1;         // 0=hi 1=lo
    int lane = cid & 63;
    int et = slot < 2 ? slot : 2 + ((slot - 2) >> 1);
    int c  = slot < 2 ? 0    : ((slot - 2) & 1);
    int m = lane & 15, q = lane >> 4;
    int e = et * 16 + m;
    int d0 = c * 32 + q * 8;
    f16x8 o;
#pragma unroll
    for (int j = 0; j < 8; ++j) {
      float v = lds[d0 + j][e];
      _Float16 h = (_Float16)v;
      o[j] = sel ? (_Float16)(v - (float)h) : h;
    }
    *(f16x8*)(dst + cid * 16) = o;
  }

  if (t < 64) {
    const int i = t;
    const float* mk = means + k * DIM;
    float acc = 0.f;
#pragma unroll 8
    for (int d = 0; d < DIM; ++d) acc = fmaf(mk[d], lds[d][i], acc);
    muP[k * DIM + i] = acc;

    double dofk = (double)dof[k];
    double s1 = digamma_d(0.5 * (dofk - (double)i));
    double s2 = log((double)lds[i][i]);
#pragma unroll
    for (int off = 32; off > 0; off >>= 1) {
      s1 += __shfl_down(s1, off);
      s2 += __shfl_down(s2, off);
    }
    if (i == 0) {
      double ak = (double)wc[k], bk = (double)wc[KCOMP + k];
      double dgab = digamma_d(ak + bk);
      double log_lambda = (double)DIM * log(2.0) + s1;
      double pc = s2
                - 0.5 * (double)DIM * LOG2PI_D
                - 0.5 * (double)DIM * log(dofk)
                + 0.5 * (log_lambda - (double)DIM / (double)mp[k]);
      t_arr[k] = digamma_d(bk) - dgab;
      g_arr[k] = digamma_d(ak) - dgab;
      pc_arr[k] = pc;
    }
  }
}

// -------- main: R24 = R22 structure (16x16 swapped-operand MFMA, 4 acc
//          chains — R23 post-mortem: 32x32's 2 chains dep-stalled, revert)
//          with 512-THREAD BLOCKS: 8 waves share one 12 KB B double-buffer.
//          First CLEAN supply doubling: per-wave work and VGPR (60)
//          unchanged; 4 blocks x 512 thr = 2048 = CU thread cap -> 32
//          waves/CU (2x R22), guaranteed by arithmetic not scheduler.
//          KSPLIT 16 so grid (64x16=1024) keeps 4 blocks/CU supplied.
//          MFMA demand/SIMD doubles to ~11.2k cyc vs ~11.4k per-ki wall.
//          Base: triangular skip (72 MFMA/ki), double-buffered async DMA,
//          per-ki barrier, R19 fold, setprio (R22), fused argmax, NO
//          fences (R8). --------------------------------------------------
__global__ __launch_bounds__(THREADS, 4) void main_kernel(
    const float* __restrict__ X,
    const char*  __restrict__ Pt,
    const float* __restrict__ muP,
    const double* __restrict__ t_arr,
    const double* __restrict__ g_arr,
    const double* __restrict__ pc_arr,
    unsigned long long* __restrict__ packed,  // [N_ROWS], zeroed by prep1
    int* __restrict__ cnt,                    // [ROWGROUPS], zeroed by prep1
    int* __restrict__ out)
{
  __shared__ uint4 bbuf[2][PT_K_BYTES / 16];  // 2 x 12 KB B double-buffer
  __shared__ __align__(16) float mup_lds[KLOCAL * DIM];
  __shared__ float cvec_lds[KCOMP];
  __shared__ int is_last;

  const int tid  = threadIdx.x;
  const int wave = tid >> 6;           // 0..7
  const int lane = tid & 63;
  const int m    = lane & 15;          // MFMA 16-index (A row = e, B col = n)
  const int q    = lane >> 4;          // quad
  const int ks   = blockIdx.y;
  const int rowbase = blockIdx.x * ROWS_PER_BLOCK + wave * ROWS_PER_WAVE;
  const int k0   = ks * KLOCAL;

  // ---- kick off async stage of k0's B image into buf 0 (12 x 1KB groups,
  //      spread over 8 waves: waves 0-3 issue 2, waves 4-7 issue 1) -------
  {
    const char* src = Pt + (size_t)k0 * PT_K_BYTES;
    for (int g = wave; g < 12; g += NWAVES)
      async_copy16(src + (g << 10) + (lane << 4),
                   (char*)&bbuf[0][g << 6]);
  }

  // wave 0: stick-breaking prefix -> cvec in LDS (6 shuffles)
  if (tid < 64) {
    double t = t_arr[tid];
    double s = t;
#pragma unroll
    for (int off = 1; off < 64; off <<= 1) {
      double v = __shfl_up(s, off);
      if (tid >= off) s += v;
    }
    cvec_lds[tid] = (float)(pc_arr[tid] + g_arr[tid] + (s - t));
  }
  // stage this block's muP slice: [k_local][e], coalesced
  for (int i = tid; i < KLOCAL * DIM; i += THREADS)
    mup_lds[i] = muP[ks * KLOCAL * DIM + i];

  // ---- load + split X rows into register-resident fragments (4 tiles) ----
  f16x8 ahi[RT][2], alo[RT][2];
#pragma unroll
  for (int rt = 0; rt < RT; ++rt) {
    int row = rowbase + rt * 16 + m;
    const float* xp = X + row * DIM;
#pragma unroll
    for (int c = 0; c < 2; ++c) {
      const float4* xq4 = (const float4*)(xp + c * 32 + q * 8);
      float4 v0 = xq4[0], v1 = xq4[1];
      float xv[8] = {v0.x, v0.y, v0.z, v0.w, v1.x, v1.y, v1.z, v1.w};
      f16x8 h, l;
#pragma unroll
      for (int j = 0; j < 8; ++j) {
        _Float16 hv = (_Float16)xv[j];
        h[j] = hv;
        l[j] = (_Float16)(xv[j] - (float)hv);
      }
      ahi[rt][c] = h;
      alo[rt][c] = l;
    }
  }

  __syncthreads();   // buf0 DMA drained (vmcnt) + cvec/mup visible

  float best = -INFINITY;
  int   bidx = 0;

  for (int ki = 0; ki < KLOCAL; ++ki) {
    const int k = k0 + ki;
    const int p = ki & 1;

    // async stage next k's B into the other buffer (lands during compute)
    if (ki + 1 < KLOCAL) {
      const char* src = Pt + (size_t)(k + 1) * PT_K_BYTES;
      for (int g = wave; g < 12; g += NWAVES)
        async_copy16(src + (g << 10) + (lane << 4),
                     (char*)&bbuf[1 - p][g << 6]);
    }

    const char* lb = (const char*)bbuf[p];
    const float ck = cvec_lds[k];
    float sq[RT];
#pragma unroll
    for (int rt = 0; rt < RT; ++rt) sq[rt] = 0.f;

    // T5: prioritize this wave while it's in the MFMA-dense phase.
    __builtin_amdgcn_s_setprio(1);
#pragma unroll
    for (int et = 0; et < 4; ++et) {
      // bias: acc[e][n] starts at -muP[e], e = et*16 + q*4 + r (per-reg)
      const f32x4 mv4 = *(const f32x4*)&mup_lds[(ki << 6) + (et << 4) + (q << 2)];
      const f32x4 mi = -mv4;
      f32x4 acc[RT];
#pragma unroll
      for (int rt = 0; rt < RT; ++rt) acc[rt] = mi;

      const int nc = (et < 2) ? 1 : 2;   // triangular skip: et<2 -> c=0 only
#pragma unroll
      for (int c = 0; c < nc; ++c) {
        const int slot = (et < 2) ? et : (2 + (et - 2) * 2 + c);
        // consecutive lanes -> consecutive 16B: 2-way bank aliasing (free)
        const char* bp = lb + (slot << 11) + (lane << 4);
        f16x8 bh = *(const f16x8*)bp;
        f16x8 bl = *(const f16x8*)(bp + 1024);
#pragma unroll
        for (int rt = 0; rt < RT; ++rt) {
          // SWAPPED: A-operand = P (hi/lo), B-operand = X (hi/lo).
          acc[rt] = __builtin_amdgcn_mfma_f32_16x16x32_f16(bh, ahi[rt][c], acc[rt], 0, 0, 0);
          acc[rt] = __builtin_amdgcn_mfma_f32_16x16x32_f16(bl, ahi[rt][c], acc[rt], 0, 0, 0);
          acc[rt] = __builtin_amdgcn_mfma_f32_16x16x32_f16(bh, alo[rt][c], acc[rt], 0, 0, 0);
        }
      }
#pragma unroll
      for (int rt = 0; rt < RT; ++rt)
#pragma unroll
        for (int r = 0; r < 4; ++r)
          sq[rt] = fmaf(acc[rt][r], acc[rt][r], sq[rt]);
    }
    __builtin_amdgcn_s_setprio(0);

    // e lives in (q, r): fold the 4 q-groups with 2 plain xor-shuffles per
    // rt; keep rt == q -> lane's row = rowbase + lane.
    float f0, f1, f2, f3;
    {
      float v0 = sq[0] + __shfl_xor(sq[0], 16); f0 = v0 + __shfl_xor(v0, 32);
      float v1 = sq[1] + __shfl_xor(sq[1], 16); f1 = v1 + __shfl_xor(v1, 32);
      float v2 = sq[2] + __shfl_xor(sq[2], 16); f2 = v2 + __shfl_xor(v2, 32);
      float v3 = sq[3] + __shfl_xor(sq[3], 16); f3 = v3 + __shfl_xor(v3, 32);
    }
    float z01 = (q & 1) ? f1 : f0;
    float z23 = (q & 1) ? f3 : f2;
    float z   = (q & 2) ? z23 : z01;

    float wv = fmaf(-0.5f, z, ck);
    if (wv > best || (wv == best && k < bidx)) { best = wv; bidx = k; }

    __syncthreads();   // next buffer's DMA drained; all waves done with buf p
  }

  // ---- publish per-row best via one atomicMax(u64), all lanes ----
  // lane's row = rowbase + lane (rt = q selection above).
  // key: monotone(float) high 32 bits, (63-k) low -> max == argmax with
  // first-max (min-k) tie-break, matching jnp.argmax.
  {
    int row = rowbase + lane;
    unsigned int b = __float_as_uint(best);
    unsigned int u = (b & 0x80000000u) ? ~b : (b | 0x80000000u);
    unsigned long long pkd = ((unsigned long long)u << 32)
                           | (unsigned long long)(63 - bidx);
    atomicMax(&packed[row], pkd);
  }
  __builtin_amdgcn_s_waitcnt(0);   // atomics ack'd at coherent point (local op)
  __syncthreads();
  if (tid == 0) {
    int old = atomicAdd(&cnt[blockIdx.x], 1);
    is_last = (old == KSPLIT - 1);
  }
  __syncthreads();
  if (is_last) {
    int n = blockIdx.x * ROWS_PER_BLOCK + tid;
    unsigned long long pv = __hip_atomic_load(&packed[n], __ATOMIC_RELAXED,
                                              __HIP_MEMORY_SCOPE_AGENT);
    out[n] = 63 - (int)(pv & 63ull);
  }
}

extern "C" void kernel_launch(void* const* d_in, const int* in_sizes, int n_in,
                              void* d_out, int out_size, void* d_ws, size_t ws_size,
                              hipStream_t stream) {
  const float* X     = (const float*)d_in[0];
  const float* means = (const float*)d_in[1];
  const float* P     = (const float*)d_in[2];
  const float* wc    = (const float*)d_in[3];
  const float* dof   = (const float*)d_in[4];
  const float* mp    = (const float*)d_in[5];
  int* out = (int*)d_out;

  // workspace layout (bytes):
  // [0,16384)           muP (4096 f32)
  // [16640,17152)       t_arr (64 f64)
  // [17152,17664)       g_arr
  // [17664,18176)       pc_arr
  // [20480,21504)       cnt (<=256 i32)
  // [24576,286720)      packed (32768 u64)
  // [294912, +786432)   Pt (64 k * 12288 B)
  char* wsb = (char*)d_ws;
  float*  muP    = (float*)(wsb);
  double* t_arr  = (double*)(wsb + 16640);
  double* g_arr  = (double*)(wsb + 17152);
  double* pc_arr = (double*)(wsb + 17664);
  int*    cnt    = (int*)(wsb + 20480);
  unsigned long long* packed = (unsigned long long*)(wsb + 24576);
  char*   Pt     = wsb + 294912;

  prep1_kernel<<<KCOMP, PREP_THREADS, 0, stream>>>(means, P, wc, dof, mp, Pt,
                                                   muP, t_arr, g_arr, pc_arr,
                                                   (uint4*)packed, (uint4*)cnt);

  dim3 grid(ROWGROUPS, KSPLIT);
  main_kernel<<<grid, THREADS, 0, stream>>>(X, Pt, muP, t_arr, g_arr, pc_arr,
                                            packed, cnt, out);
}

// Round 11
// 107.343 us; speedup vs baseline: 1.0101x; 1.0101x over previous
//
#include <hip/hip_runtime.h>
#include <math.h>

#define N_ROWS 32768
#define DIM 64
#define KCOMP 64
#define KSPLIT 8
#define KLOCAL 8           // KCOMP / KSPLIT
#define EPOCHS (KLOCAL / 2)
#define THREADS 256        // 4 waves
#define PREP_THREADS 256
#define RT 4               // row-tiles of 16 per wave
#define ROWS_PER_WAVE 64
#define ROWS_PER_BLOCK 256 // 4 waves * 64 rows
#define ROWGROUPS (N_ROWS / ROWS_PER_BLOCK)   // 128

// P is UPPER-TRIANGULAR (P[d][e]=0 for d>e): of the 8 (et,c) blocks,
// (et=0,c=1) and (et=1,c=1) are all-zero. Pt packs the 6 nonzero slots:
//   slot: 0=(et0,c0) 1=(et1,c0) 2=(et2,c0) 3=(et2,c1) 4=(et3,c0) 5=(et3,c1)
// Per k: 6 slots x 2048 B = 12288 B:
//   slot block: [hi: 64 chunks x 16 B, chunk=lane] [lo: same, +1024]
//   chunk(lane) holds f16 P[d = c*32 + q*8 + j][e = et*16 + m], j=0..7
// Skipping the zero blocks is BIT-IDENTICAL: mfma(0, B, acc) adds +/-0.
#define PT_K_BYTES 12288

#define LOG2PI_D 1.8378770664093454836

typedef _Float16 f16x8 __attribute__((ext_vector_type(8)));
typedef float f32x4 __attribute__((ext_vector_type(4)));

#define AS1 __attribute__((address_space(1)))
#define AS3 __attribute__((address_space(3)))

// async 16B/lane global->LDS DMA: lds dest wave-uniform; lane i -> base+i*16
__device__ __forceinline__ void async_copy16(const char* g, char* l) {
  __builtin_amdgcn_global_load_lds((const AS1 unsigned int*)g,
                                   (AS3 unsigned int*)l, 16, 0, 0);
}

// ---------------- digamma (double, recurrence + asymptotic) ----------------
__device__ __forceinline__ double digamma_d(double x) {
  double r = 0.0;
  while (x < 6.0) { r -= 1.0 / x; x += 1.0; }
  double inv = 1.0 / x;
  double inv2 = inv * inv;
  double s = log(x) - 0.5 * inv
      - inv2 * (1.0/12.0 - inv2 * (1.0/120.0 - inv2 * (1.0/252.0
      - inv2 * (1.0/240.0 - inv2 * (1.0/132.0)))));
  return r + s;
}

// ------- prep1: one block per k. LDS-staged transpose repack of P into Pt
//         (6 nonzero slots, R22 map). Wave 0: muP, log-det, digamma sums,
//         stick-breaking terms. Also zeroes packed/cnt (fused memset). ----
__global__ void prep1_kernel(const float* __restrict__ means,
                             const float* __restrict__ P,
                             const float* __restrict__ wc,
                             const float* __restrict__ dof,
                             const float* __restrict__ mp,
                             char*   __restrict__ Pt,
                             float*  __restrict__ muP,
                             double* __restrict__ t_arr,
                             double* __restrict__ g_arr,
                             double* __restrict__ pc_arr,
                             uint4*  __restrict__ packed4,  // 16384 x 16 B
                             uint4*  __restrict__ cnt4)     // 64 x 16 B
{
  __shared__ float lds[DIM][DIM + 1];
  const int k = blockIdx.x;
  const int t = threadIdx.x;
  const float* Pk = P + k * DIM * DIM;

  // fused memset: zero packed (64 blk x 256 thr x 16 B = 256 KB) + cnt
  const uint4 z4 = {0u, 0u, 0u, 0u};
  packed4[k * PREP_THREADS + t] = z4;
  if (k == 0 && t < 64) cnt4[t] = z4;

  for (int i = t; i < DIM * DIM; i += PREP_THREADS)
    lds[i >> 6][i & 63] = Pk[i];
  __syncthreads();

  char* dst = Pt + (size_t)k * PT_K_BYTES;
#pragma unroll
  for (int cc = 0; cc < 3; ++cc) {                // 768 cids = 6 slots x 2 KB
    int cid  = cc * PREP_THREADS + t;
    int slot = cid >> 7;               // 0..5
    int sel  = (cid >> 6) & 1;         // 0=hi 1=lo
    int lane = cid & 63;
    int et = slot < 2 ? slot : 2 + ((slot - 2) >> 1);
    int c  = slot < 2 ? 0    : ((slot - 2) & 1);
    int m = lane & 15, q = lane >> 4;
    int e = et * 16 + m;
    int d0 = c * 32 + q * 8;
    f16x8 o;
#pragma unroll
    for (int j = 0; j < 8; ++j) {
      float v = lds[d0 + j][e];
      _Float16 h = (_Float16)v;
      o[j] = sel ? (_Float16)(v - (float)h) : h;
    }
    *(f16x8*)(dst + cid * 16) = o;
  }

  if (t < 64) {
    const int i = t;
    const float* mk = means + k * DIM;
    float acc = 0.f;
#pragma unroll 8
    for (int d = 0; d < DIM; ++d) acc = fmaf(mk[d], lds[d][i], acc);
    muP[k * DIM + i] = acc;

    double dofk = (double)dof[k];
    double s1 = digamma_d(0.5 * (dofk - (double)i));
    double s2 = log((double)lds[i][i]);
#pragma unroll
    for (int off = 32; off > 0; off >>= 1) {
      s1 += __shfl_down(s1, off);
      s2 += __shfl_down(s2, off);
    }
    if (i == 0) {
      double ak = (double)wc[k], bk = (double)wc[KCOMP + k];
      double dgab = digamma_d(ak + bk);
      double log_lambda = (double)DIM * log(2.0) + s1;
      double pc = s2
                - 0.5 * (double)DIM * LOG2PI_D
                - 0.5 * (double)DIM * log(dofk)
                + 0.5 * (log_lambda - (double)DIM / (double)mp[k]);
      t_arr[k] = digamma_d(bk) - dgab;
      g_arr[k] = digamma_d(ak) - dgab;
      pc_arr[k] = pc;
    }
  }
}

// -------- main: R25 = R22 (best: 16x16 swapped-operand, 4 chains, KSPLIT=8,
//          256 thr — R24's 8-wave/KSPLIT-16 reverted after 4th failed supply
//          push) + 2-ki EPOCHS: double-wide LDS buffers (2 x 24 KB; k and
//          k+1 images are CONTIGUOUS in Pt so the DMA pattern is unchanged,
//          6 insts/wave/epoch), both ki's MFMA phases back-to-back in one
//          setprio region (independent acc chains -> scheduler overlaps
//          ki1 ds_reads under ki0 MFMAs), folds batched, ONE barrier per
//          epoch (4 total, was 8). Per-k math instruction-identical ->
//          absmax 0. LDS 51.5 KB -> 3 blocks/CU (>= measured residency).
//          Base: triangular skip (72 MFMA/ki), R19 fold, fused argmax,
//          NO fences (R8). -----------------------------------------------
__global__ __launch_bounds__(THREADS, 4) void main_kernel(
    const float* __restrict__ X,
    const char*  __restrict__ Pt,
    const float* __restrict__ muP,
    const double* __restrict__ t_arr,
    const double* __restrict__ g_arr,
    const double* __restrict__ pc_arr,
    unsigned long long* __restrict__ packed,  // [N_ROWS], zeroed by prep1
    int* __restrict__ cnt,                    // [ROWGROUPS], zeroed by prep1
    int* __restrict__ out)
{
  __shared__ uint4 bbuf[2][2 * PT_K_BYTES / 16];  // 2 x 24 KB (epoch pair)
  __shared__ __align__(16) float mup_lds[KLOCAL * DIM];
  __shared__ float cvec_lds[KCOMP];
  __shared__ int is_last;

  const int tid  = threadIdx.x;
  const int wave = tid >> 6;           // 0..3
  const int lane = tid & 63;
  const int m    = lane & 15;          // MFMA 16-index (A row = e, B col = n)
  const int q    = lane >> 4;          // quad
  const int ks   = blockIdx.y;
  const int rowbase = blockIdx.x * ROWS_PER_BLOCK + wave * ROWS_PER_WAVE;
  const int k0   = ks * KLOCAL;

  // ---- kick off async stage of epoch 0 (k0,k0+1: 24 KB, 6 insts/wave) ----
  {
    const char* src = Pt + (size_t)k0 * PT_K_BYTES;
#pragma unroll
    for (int i = 0; i < 6; ++i) {
      const int g = wave * 6 + i;                    // 1 KB group, uniform/wave
      async_copy16(src + (g << 10) + (lane << 4),
                   (char*)bbuf[0] + (g << 10));
    }
  }

  // wave 0: stick-breaking prefix -> cvec in LDS (6 shuffles)
  if (tid < 64) {
    double t = t_arr[tid];
    double s = t;
#pragma unroll
    for (int off = 1; off < 64; off <<= 1) {
      double v = __shfl_up(s, off);
      if (tid >= off) s += v;
    }
    cvec_lds[tid] = (float)(pc_arr[tid] + g_arr[tid] + (s - t));
  }
  // stage this block's muP slice: [k_local][e], coalesced
  for (int i = tid; i < KLOCAL * DIM; i += THREADS)
    mup_lds[i] = muP[ks * KLOCAL * DIM + i];

  // ---- load + split X rows into register-resident fragments (4 tiles) ----
  f16x8 ahi[RT][2], alo[RT][2];
#pragma unroll
  for (int rt = 0; rt < RT; ++rt) {
    int row = rowbase + rt * 16 + m;
    const float* xp = X + row * DIM;
#pragma unroll
    for (int c = 0; c < 2; ++c) {
      const float4* xq4 = (const float4*)(xp + c * 32 + q * 8);
      float4 v0 = xq4[0], v1 = xq4[1];
      float xv[8] = {v0.x, v0.y, v0.z, v0.w, v1.x, v1.y, v1.z, v1.w};
      f16x8 h, l;
#pragma unroll
      for (int j = 0; j < 8; ++j) {
        _Float16 hv = (_Float16)xv[j];
        h[j] = hv;
        l[j] = (_Float16)(xv[j] - (float)hv);
      }
      ahi[rt][c] = h;
      alo[rt][c] = l;
    }
  }

  __syncthreads();   // epoch-0 DMA drained (vmcnt) + cvec/mup visible

  float best = -INFINITY;
  int   bidx = 0;

  for (int ep = 0; ep < EPOCHS; ++ep) {
    const int p = ep & 1;

    // async stage next epoch's pair into the other buffer (during compute)
    if (ep + 1 < EPOCHS) {
      const char* src = Pt + (size_t)(k0 + 2 * (ep + 1)) * PT_K_BYTES;
#pragma unroll
      for (int i = 0; i < 6; ++i) {
        const int g = wave * 6 + i;
        async_copy16(src + (g << 10) + (lane << 4),
                     (char*)bbuf[1 - p] + (g << 10));
      }
    }

    float sq2[2][RT];
#pragma unroll
    for (int hh = 0; hh < 2; ++hh)
#pragma unroll
      for (int rt = 0; rt < RT; ++rt) sq2[hh][rt] = 0.f;

    // T5: prioritize through the long (2-ki) MFMA-dense phase.
    __builtin_amdgcn_s_setprio(1);
#pragma unroll
    for (int hh = 0; hh < 2; ++hh) {                // ki = 2*ep + hh
      const int ki = 2 * ep + hh;
      const char* lb = (const char*)bbuf[p] + hh * PT_K_BYTES;
#pragma unroll
      for (int et = 0; et < 4; ++et) {
        // bias: acc[e][n] starts at -muP[e], e = et*16 + q*4 + r (per-reg)
        const f32x4 mv4 = *(const f32x4*)&mup_lds[(ki << 6) + (et << 4) + (q << 2)];
        const f32x4 mi = -mv4;
        f32x4 acc[RT];
#pragma unroll
        for (int rt = 0; rt < RT; ++rt) acc[rt] = mi;

        const int nc = (et < 2) ? 1 : 2;  // triangular skip: et<2 -> c=0 only
#pragma unroll
        for (int c = 0; c < nc; ++c) {
          const int slot = (et < 2) ? et : (2 + (et - 2) * 2 + c);
          // consecutive lanes -> consecutive 16B: 2-way bank aliasing (free)
          const char* bp = lb + (slot << 11) + (lane << 4);
          f16x8 bh = *(const f16x8*)bp;
          f16x8 bl = *(const f16x8*)(bp + 1024);
#pragma unroll
          for (int rt = 0; rt < RT; ++rt) {
            // SWAPPED: A-operand = P (hi/lo), B-operand = X (hi/lo).
            acc[rt] = __builtin_amdgcn_mfma_f32_16x16x32_f16(bh, ahi[rt][c], acc[rt], 0, 0, 0);
            acc[rt] = __builtin_amdgcn_mfma_f32_16x16x32_f16(bl, ahi[rt][c], acc[rt], 0, 0, 0);
            acc[rt] = __builtin_amdgcn_mfma_f32_16x16x32_f16(bh, alo[rt][c], acc[rt], 0, 0, 0);
          }
        }
#pragma unroll
        for (int rt = 0; rt < RT; ++rt)
#pragma unroll
          for (int r = 0; r < 4; ++r)
            sq2[hh][rt] = fmaf(acc[rt][r], acc[rt][r], sq2[hh][rt]);
      }
    }
    __builtin_amdgcn_s_setprio(0);

    // batched folds for both ki (independent shuffle chains overlap)
#pragma unroll
    for (int hh = 0; hh < 2; ++hh) {
      const int k = k0 + 2 * ep + hh;
      const float ck = cvec_lds[k];
      float f0, f1, f2, f3;
      {
        float v0 = sq2[hh][0] + __shfl_xor(sq2[hh][0], 16); f0 = v0 + __shfl_xor(v0, 32);
        float v1 = sq2[hh][1] + __shfl_xor(sq2[hh][1], 16); f1 = v1 + __shfl_xor(v1, 32);
        float v2 = sq2[hh][2] + __shfl_xor(sq2[hh][2], 16); f2 = v2 + __shfl_xor(v2, 32);
        float v3 = sq2[hh][3] + __shfl_xor(sq2[hh][3], 16); f3 = v3 + __shfl_xor(v3, 32);
      }
      float z01 = (q & 1) ? f1 : f0;
      float z23 = (q & 1) ? f3 : f2;
      float z   = (q & 2) ? z23 : z01;

      float wv = fmaf(-0.5f, z, ck);
      if (wv > best || (wv == best && k < bidx)) { best = wv; bidx = k; }
    }

    __syncthreads();   // next epoch's DMA drained; all waves done with buf p
  }

  // ---- publish per-row best via one atomicMax(u64), all 64 lanes ----
  // lane's row = rowbase + lane (rt = q selection in the fold).
  // key: monotone(float) high 32 bits, (63-k) low -> max == argmax with
  // first-max (min-k) tie-break, matching jnp.argmax.
  {
    int row = rowbase + lane;
    unsigned int b = __float_as_uint(best);
    unsigned int u = (b & 0x80000000u) ? ~b : (b | 0x80000000u);
    unsigned long long pkd = ((unsigned long long)u << 32)
                           | (unsigned long long)(63 - bidx);
    atomicMax(&packed[row], pkd);
  }
  __builtin_amdgcn_s_waitcnt(0);   // atomics ack'd at coherent point (local op)
  __syncthreads();
  if (tid == 0) {
    int old = atomicAdd(&cnt[blockIdx.x], 1);
    is_last = (old == KSPLIT - 1);
  }
  __syncthreads();
  if (is_last) {
    int n = blockIdx.x * ROWS_PER_BLOCK + tid;
    unsigned long long pv = __hip_atomic_load(&packed[n], __ATOMIC_RELAXED,
                                              __HIP_MEMORY_SCOPE_AGENT);
    out[n] = 63 - (int)(pv & 63ull);
  }
}

extern "C" void kernel_launch(void* const* d_in, const int* in_sizes, int n_in,
                              void* d_out, int out_size, void* d_ws, size_t ws_size,
                              hipStream_t stream) {
  const float* X     = (const float*)d_in[0];
  const float* means = (const float*)d_in[1];
  const float* P     = (const float*)d_in[2];
  const float* wc    = (const float*)d_in[3];
  const float* dof   = (const float*)d_in[4];
  const float* mp    = (const float*)d_in[5];
  int* out = (int*)d_out;

  // workspace layout (bytes):
  // [0,16384)           muP (4096 f32)
  // [16640,17152)       t_arr (64 f64)
  // [17152,17664)       g_arr
  // [17664,18176)       pc_arr
  // [20480,21504)       cnt (<=256 i32)
  // [24576,286720)      packed (32768 u64)
  // [294912, +786432)   Pt (64 k * 12288 B)
  char* wsb = (char*)d_ws;
  float*  muP    = (float*)(wsb);
  double* t_arr  = (double*)(wsb + 16640);
  double* g_arr  = (double*)(wsb + 17152);
  double* pc_arr = (double*)(wsb + 17664);
  int*    cnt    = (int*)(wsb + 20480);
  unsigned long long* packed = (unsigned long long*)(wsb + 24576);
  char*   Pt     = wsb + 294912;

  prep1_kernel<<<KCOMP, PREP_THREADS, 0, stream>>>(means, P, wc, dof, mp, Pt,
                                                   muP, t_arr, g_arr, pc_arr,
                                                   (uint4*)packed, (uint4*)cnt);

  dim3 grid(ROWGROUPS, KSPLIT);
  main_kernel<<<grid, THREADS, 0, stream>>>(X, Pt, muP, t_arr, g_arr, pc_arr,
                                            packed, cnt, out);
}

// Round 12
// 105.179 us; speedup vs baseline: 1.0309x; 1.0206x over previous
//
#include <hip/hip_runtime.h>
#include <math.h>

#define N_ROWS 32768
#define DIM 64
#define KCOMP 64
#define KSPLIT 8
#define KLOCAL 8           // KCOMP / KSPLIT
#define THREADS 256        // 4 waves
#define PREP_THREADS 256
#define RT 4               // row-tiles of 16 per wave
#define ROWS_PER_WAVE 64
#define ROWS_PER_BLOCK 256 // 4 waves * 64 rows
#define ROWGROUPS (N_ROWS / ROWS_PER_BLOCK)   // 128

// P is UPPER-TRIANGULAR (P[d][e]=0 for d>e): of the 8 (et,c) blocks,
// (et=0,c=1) and (et=1,c=1) are all-zero. Pt packs the 6 nonzero slots:
//   slot: 0=(et0,c0) 1=(et1,c0) 2=(et2,c0) 3=(et2,c1) 4=(et3,c0) 5=(et3,c1)
// Per k: 6 slots x 2048 B = 12288 B:
//   slot block: [hi: 64 chunks x 16 B, chunk=lane] [lo: same, +1024]
//   chunk(lane) holds f16 P[d = c*32 + q*8 + j][e = et*16 + m], j=0..7
// Skipping the zero blocks is BIT-IDENTICAL: mfma(0, B, acc) adds +/-0.
#define PT_K_BYTES 12288

#define LOG2PI_D 1.8378770664093454836

typedef _Float16 f16x8 __attribute__((ext_vector_type(8)));
typedef float f32x4 __attribute__((ext_vector_type(4)));

#define AS1 __attribute__((address_space(1)))
#define AS3 __attribute__((address_space(3)))

// async 16B/lane global->LDS DMA: lds dest wave-uniform; lane i -> base+i*16
__device__ __forceinline__ void async_copy16(const char* g, char* l) {
  __builtin_amdgcn_global_load_lds((const AS1 unsigned int*)g,
                                   (AS3 unsigned int*)l, 16, 0, 0);
}

// ---------------- digamma (double, recurrence + asymptotic) ----------------
__device__ __forceinline__ double digamma_d(double x) {
  double r = 0.0;
  while (x < 6.0) { r -= 1.0 / x; x += 1.0; }
  double inv = 1.0 / x;
  double inv2 = inv * inv;
  double s = log(x) - 0.5 * inv
      - inv2 * (1.0/12.0 - inv2 * (1.0/120.0 - inv2 * (1.0/252.0
      - inv2 * (1.0/240.0 - inv2 * (1.0/132.0)))));
  return r + s;
}

// ------- prep1: one block per k. LDS-staged transpose repack of P into Pt
//         (6 nonzero slots only). Wave 0: muP, log-det, digamma sums,
//         stick-breaking terms. Also zeroes packed/cnt (fused memset). ----
__global__ void prep1_kernel(const float* __restrict__ means,
                             const float* __restrict__ P,
                             const float* __restrict__ wc,
                             const float* __restrict__ dof,
                             const float* __restrict__ mp,
                             char*   __restrict__ Pt,
                             float*  __restrict__ muP,
                             double* __restrict__ t_arr,
                             double* __restrict__ g_arr,
                             double* __restrict__ pc_arr,
                             uint4*  __restrict__ packed4,  // 16384 x 16 B
                             uint4*  __restrict__ cnt4)     // 64 x 16 B
{
  __shared__ float lds[DIM][DIM + 1];
  const int k = blockIdx.x;
  const int t = threadIdx.x;
  const float* Pk = P + k * DIM * DIM;

  // fused memset: zero packed (64 blk x 256 thr x 16 B = 256 KB) + cnt
  const uint4 z4 = {0u, 0u, 0u, 0u};
  packed4[k * PREP_THREADS + t] = z4;
  if (k == 0 && t < 64) cnt4[t] = z4;

  for (int i = t; i < DIM * DIM; i += PREP_THREADS)
    lds[i >> 6][i & 63] = Pk[i];
  __syncthreads();

  char* dst = Pt + (size_t)k * PT_K_BYTES;
#pragma unroll
  for (int cc = 0; cc < 3; ++cc) {                // 768 cids = 6 slots x 2 KB
    int cid  = cc * PREP_THREADS + t;
    int slot = cid >> 7;               // 0..5
    int sel  = (cid >> 6) & 1;         // 0=hi 1=lo
    int lane = cid & 63;
    int et = slot < 2 ? slot : 2 + ((slot - 2) >> 1);
    int c  = slot < 2 ? 0    : ((slot - 2) & 1);
    int m = lane & 15, q = lane >> 4;
    int e = et * 16 + m;
    int d0 = c * 32 + q * 8;
    f16x8 o;
#pragma unroll
    for (int j = 0; j < 8; ++j) {
      float v = lds[d0 + j][e];
      _Float16 h = (_Float16)v;
      o[j] = sel ? (_Float16)(v - (float)h) : h;
    }
    *(f16x8*)(dst + cid * 16) = o;
  }

  if (t < 64) {
    const int i = t;
    const float* mk = means + k * DIM;
    float acc = 0.f;
#pragma unroll 8
    for (int d = 0; d < DIM; ++d) acc = fmaf(mk[d], lds[d][i], acc);
    muP[k * DIM + i] = acc;

    double dofk = (double)dof[k];
    double s1 = digamma_d(0.5 * (dofk - (double)i));
    double s2 = log((double)lds[i][i]);
#pragma unroll
    for (int off = 32; off > 0; off >>= 1) {
      s1 += __shfl_down(s1, off);
      s2 += __shfl_down(s2, off);
    }
    if (i == 0) {
      double ak = (double)wc[k], bk = (double)wc[KCOMP + k];
      double dgab = digamma_d(ak + bk);
      double log_lambda = (double)DIM * log(2.0) + s1;
      double pc = s2
                - 0.5 * (double)DIM * LOG2PI_D
                - 0.5 * (double)DIM * log(dofk)
                + 0.5 * (log_lambda - (double)DIM / (double)mp[k]);
      t_arr[k] = digamma_d(bk) - dgab;
      g_arr[k] = digamma_d(ak) - dgab;
      pc_arr[k] = pc;
    }
  }
}

// -------- main: R26 = R22 exact revert (best measured: total 105.4 us,
//          main ~38 us). Session ledger: work removal paid (R18 triangular
//          -15%, R19 swapped-operand fold -6%); every schedule lever failed
//          (R15 barrier-free neutral; R16/R17/R21/R24 supply pushes hurt —
//          occupancy is register-capped at ~3-4 waves/SIMD by the 64-VGPR
//          A-frags + acc; R23 32x32 shape dep-stalled; R25 2-ki epochs
//          spilled to VGPR=128). Structure: 16x16 swapped-operand f16-split
//          MFMA (72/ki after triangular skip), double-buffered LDS B via
//          async global_load_lds, per-ki barrier, R19 2-shuffle fold,
//          setprio around MFMA phase, fused argmax via device-scope
//          atomics, NO fences (R8). ---------------------------------------
__global__ __launch_bounds__(THREADS, 4) void main_kernel(
    const float* __restrict__ X,
    const char*  __restrict__ Pt,
    const float* __restrict__ muP,
    const double* __restrict__ t_arr,
    const double* __restrict__ g_arr,
    const double* __restrict__ pc_arr,
    unsigned long long* __restrict__ packed,  // [N_ROWS], zeroed by prep1
    int* __restrict__ cnt,                    // [ROWGROUPS], zeroed by prep1
    int* __restrict__ out)
{
  __shared__ uint4 bbuf[2][PT_K_BYTES / 16];  // 2 x 12 KB B double-buffer
  __shared__ __align__(16) float mup_lds[KLOCAL * DIM];
  __shared__ float cvec_lds[KCOMP];
  __shared__ int is_last;

  const int tid  = threadIdx.x;
  const int wave = tid >> 6;           // 0..3
  const int lane = tid & 63;
  const int m    = lane & 15;          // MFMA 16-index (A row = e, B col = n)
  const int q    = lane >> 4;          // quad
  const int ks   = blockIdx.y;
  const int rowbase = blockIdx.x * ROWS_PER_BLOCK + wave * ROWS_PER_WAVE;
  const int k0   = ks * KLOCAL;

  // ---- kick off async stage of k0's B image into buf 0 (3 DMA insts/wave) --
  {
    const char* src = Pt + (size_t)k0 * PT_K_BYTES;
#pragma unroll
    for (int i = 0; i < 3; ++i) {
      const int g = wave * 3 + i;                    // 1 KB group, uniform/wave
      async_copy16(src + (g << 10) + (lane << 4),
                   (char*)&bbuf[0][g << 6]);
    }
  }

  // wave 0: stick-breaking prefix -> cvec in LDS (6 shuffles)
  if (tid < 64) {
    double t = t_arr[tid];
    double s = t;
#pragma unroll
    for (int off = 1; off < 64; off <<= 1) {
      double v = __shfl_up(s, off);
      if (tid >= off) s += v;
    }
    cvec_lds[tid] = (float)(pc_arr[tid] + g_arr[tid] + (s - t));
  }
  // stage this block's muP slice: [k_local][e], coalesced
  for (int i = tid; i < KLOCAL * DIM; i += THREADS)
    mup_lds[i] = muP[ks * KLOCAL * DIM + i];

  // ---- load + split X rows into register-resident fragments (4 tiles) ----
  f16x8 ahi[RT][2], alo[RT][2];
#pragma unroll
  for (int rt = 0; rt < RT; ++rt) {
    int row = rowbase + rt * 16 + m;
    const float* xp = X + row * DIM;
#pragma unroll
    for (int c = 0; c < 2; ++c) {
      const float4* xq4 = (const float4*)(xp + c * 32 + q * 8);
      float4 v0 = xq4[0], v1 = xq4[1];
      float xv[8] = {v0.x, v0.y, v0.z, v0.w, v1.x, v1.y, v1.z, v1.w};
      f16x8 h, l;
#pragma unroll
      for (int j = 0; j < 8; ++j) {
        _Float16 hv = (_Float16)xv[j];
        h[j] = hv;
        l[j] = (_Float16)(xv[j] - (float)hv);
      }
      ahi[rt][c] = h;
      alo[rt][c] = l;
    }
  }

  __syncthreads();   // buf0 DMA drained (vmcnt) + cvec/mup visible

  float best = -INFINITY;
  int   bidx = 0;

  for (int ki = 0; ki < KLOCAL; ++ki) {
    const int k = k0 + ki;
    const int p = ki & 1;

    // async stage next k's B into the other buffer (lands during compute)
    if (ki + 1 < KLOCAL) {
      const char* src = Pt + (size_t)(k + 1) * PT_K_BYTES;
#pragma unroll
      for (int i = 0; i < 3; ++i) {
        const int g = wave * 3 + i;
        async_copy16(src + (g << 10) + (lane << 4),
                     (char*)&bbuf[1 - p][g << 6]);
      }
    }

    const char* lb = (const char*)bbuf[p];
    const float ck = cvec_lds[k];
    float sq[RT];
#pragma unroll
    for (int rt = 0; rt < RT; ++rt) sq[rt] = 0.f;

    // T5: prioritize this wave while it's in the MFMA-dense phase.
    __builtin_amdgcn_s_setprio(1);
#pragma unroll
    for (int et = 0; et < 4; ++et) {
      // bias: acc[e][n] starts at -muP[e], e = et*16 + q*4 + r (per-reg)
      const f32x4 mv4 = *(const f32x4*)&mup_lds[(ki << 6) + (et << 4) + (q << 2)];
      const f32x4 mi = -mv4;
      f32x4 acc[RT];
#pragma unroll
      for (int rt = 0; rt < RT; ++rt) acc[rt] = mi;

      const int nc = (et < 2) ? 1 : 2;   // triangular skip: et<2 -> c=0 only
#pragma unroll
      for (int c = 0; c < nc; ++c) {
        const int slot = (et < 2) ? et : (2 + (et - 2) * 2 + c);
        // consecutive lanes -> consecutive 16B: 2-way bank aliasing (free)
        const char* bp = lb + (slot << 11) + (lane << 4);
        f16x8 bh = *(const f16x8*)bp;
        f16x8 bl = *(const f16x8*)(bp + 1024);
#pragma unroll
        for (int rt = 0; rt < RT; ++rt) {
          // SWAPPED: A-operand = P (hi/lo), B-operand = X (hi/lo).
          acc[rt] = __builtin_amdgcn_mfma_f32_16x16x32_f16(bh, ahi[rt][c], acc[rt], 0, 0, 0);
          acc[rt] = __builtin_amdgcn_mfma_f32_16x16x32_f16(bl, ahi[rt][c], acc[rt], 0, 0, 0);
          acc[rt] = __builtin_amdgcn_mfma_f32_16x16x32_f16(bh, alo[rt][c], acc[rt], 0, 0, 0);
        }
      }
#pragma unroll
      for (int rt = 0; rt < RT; ++rt)
#pragma unroll
        for (int r = 0; r < 4; ++r)
          sq[rt] = fmaf(acc[rt][r], acc[rt][r], sq[rt]);
    }
    __builtin_amdgcn_s_setprio(0);

    // e lives in (q, r): fold the 4 q-groups with 2 plain xor-shuffles per
    // rt; keep rt == q -> lane's row = rowbase + lane.
    float f0, f1, f2, f3;
    {
      float v0 = sq[0] + __shfl_xor(sq[0], 16); f0 = v0 + __shfl_xor(v0, 32);
      float v1 = sq[1] + __shfl_xor(sq[1], 16); f1 = v1 + __shfl_xor(v1, 32);
      float v2 = sq[2] + __shfl_xor(sq[2], 16); f2 = v2 + __shfl_xor(v2, 32);
      float v3 = sq[3] + __shfl_xor(sq[3], 16); f3 = v3 + __shfl_xor(v3, 32);
    }
    float z01 = (q & 1) ? f1 : f0;
    float z23 = (q & 1) ? f3 : f2;
    float z   = (q & 2) ? z23 : z01;

    float wv = fmaf(-0.5f, z, ck);
    if (wv > best || (wv == best && k < bidx)) { best = wv; bidx = k; }

    __syncthreads();   // next buffer's DMA drained; all waves done with buf p
  }

  // ---- publish per-row best via one atomicMax(u64), all 64 lanes ----
  // lane's row = rowbase + lane (rt = q selection above).
  // key: monotone(float) high 32 bits, (63-k) low -> max == argmax with
  // first-max (min-k) tie-break, matching jnp.argmax.
  {
    int row = rowbase + lane;
    unsigned int b = __float_as_uint(best);
    unsigned int u = (b & 0x80000000u) ? ~b : (b | 0x80000000u);
    unsigned long long pkd = ((unsigned long long)u << 32)
                           | (unsigned long long)(63 - bidx);
    atomicMax(&packed[row], pkd);
  }
  __builtin_amdgcn_s_waitcnt(0);   // atomics ack'd at coherent point (local op)
  __syncthreads();
  if (tid == 0) {
    int old = atomicAdd(&cnt[blockIdx.x], 1);
    is_last = (old == KSPLIT - 1);
  }
  __syncthreads();
  if (is_last) {
    int n = blockIdx.x * ROWS_PER_BLOCK + tid;
    unsigned long long pv = __hip_atomic_load(&packed[n], __ATOMIC_RELAXED,
                                              __HIP_MEMORY_SCOPE_AGENT);
    out[n] = 63 - (int)(pv & 63ull);
  }
}

extern "C" void kernel_launch(void* const* d_in, const int* in_sizes, int n_in,
                              void* d_out, int out_size, void* d_ws, size_t ws_size,
                              hipStream_t stream) {
  const float* X     = (const float*)d_in[0];
  const float* means = (const float*)d_in[1];
  const float* P     = (const float*)d_in[2];
  const float* wc    = (const float*)d_in[3];
  const float* dof   = (const float*)d_in[4];
  const float* mp    = (const float*)d_in[5];
  int* out = (int*)d_out;

  // workspace layout (bytes):
  // [0,16384)           muP (4096 f32)
  // [16640,17152)       t_arr (64 f64)
  // [17152,17664)       g_arr
  // [17664,18176)       pc_arr
  // [20480,21504)       cnt (<=256 i32)
  // [24576,286720)      packed (32768 u64)
  // [294912, +786432)   Pt (64 k * 12288 B)
  char* wsb = (char*)d_ws;
  float*  muP    = (float*)(wsb);
  double* t_arr  = (double*)(wsb + 16640);
  double* g_arr  = (double*)(wsb + 17152);
  double* pc_arr = (double*)(wsb + 17664);
  int*    cnt    = (int*)(wsb + 20480);
  unsigned long long* packed = (unsigned long long*)(wsb + 24576);
  char*   Pt     = wsb + 294912;

  prep1_kernel<<<KCOMP, PREP_THREADS, 0, stream>>>(means, P, wc, dof, mp, Pt,
                                                   muP, t_arr, g_arr, pc_arr,
                                                   (uint4*)packed, (uint4*)cnt);

  dim3 grid(ROWGROUPS, KSPLIT);
  main_kernel<<<grid, THREADS, 0, stream>>>(X, Pt, muP, t_arr, g_arr, pc_arr,
                                            packed, cnt, out);
}